// Round 12
// baseline (180.257 us; speedup 1.0000x reference)
//
#include <hip/hip_runtime.h>
#include <stdint.h>
#include <math.h>

#define B_ 2
#define S_ 2048
#define D_ 1024
#define H_ 16
#define HD_ 64
#define KVBLK 64

typedef __bf16 bf16_t;
typedef __bf16 bf16x4 __attribute__((ext_vector_type(4)));
typedef __bf16 bf16x8 __attribute__((ext_vector_type(8)));
typedef float f32x4 __attribute__((ext_vector_type(4)));
typedef float f32x16 __attribute__((ext_vector_type(16)));
typedef float float4v __attribute__((ext_vector_type(4)));

#define L2E 1.4426950408889634f
#define NINF (-__builtin_inff())

__device__ __forceinline__ void gload_lds16(const bf16_t* g, bf16_t* l) {
  __builtin_amdgcn_global_load_lds((const __attribute__((address_space(1))) void*)g,
                                   (__attribute__((address_space(3))) void*)l, 16, 0, 0);
}

__device__ __forceinline__ uint32_t packbf(float a, float b) {
  union { __bf16 h[2]; uint32_t u; } cvt;
  cvt.h[0] = (__bf16)a; cvt.h[1] = (__bf16)b;
  return cvt.u;
}

// ---------------- fused cast f32 -> bf16 for all three inputs (vector x4) ----------------
__global__ void cast3_bf16_kernel(const float* __restrict__ s0, bf16_t* __restrict__ d0, int n0,
                                  const float* __restrict__ s1, bf16_t* __restrict__ d1, int n1,
                                  const float* __restrict__ s2, bf16_t* __restrict__ d2, int n2) {
  int i = blockIdx.x * blockDim.x + threadIdx.x;
  int stride = gridDim.x * blockDim.x;
  int tot = n0 + n1 + n2;
  for (; i < tot; i += stride) {
    const float* s; bf16_t* d; int j = i;
    if (j < n0) { s = s0; d = d0; }
    else if ((j -= n0) < n1) { s = s1; d = d1; }
    else { j -= n1; s = s2; d = d2; }
    float4v f = *(const float4v*)(s + (size_t)j * 4);
    bf16x4 o;
    o[0] = (__bf16)f[0]; o[1] = (__bf16)f[1]; o[2] = (__bf16)f[2]; o[3] = (__bf16)f[3];
    *(bf16x4*)(d + (size_t)j * 4) = o;
  }
}

// ---------------- small GEMM (128^2, m97 structure) for gemm2 ----------------
template <typename OutT>
__global__ __launch_bounds__(256) void gemm_bt(const bf16_t* __restrict__ A,
                                               const bf16_t* __restrict__ Bm,
                                               OutT* __restrict__ C,
                                               int M, int N, int K) {
  __shared__ bf16_t As[128 * 32];
  __shared__ bf16_t Bs[128 * 32];
  const int t = threadIdx.x;
  const int lane = t & 63, wave = t >> 6;
  const int wr = wave >> 1, wc = wave & 1;
  const int qr = lane & 15, g = lane >> 4;
  const int bm = blockIdx.x, bn = blockIdx.y;

  f32x4 acc[4][4];
#pragma unroll
  for (int m = 0; m < 4; m++)
#pragma unroll
    for (int n = 0; n < 4; n++) acc[m][n] = (f32x4){0.f, 0.f, 0.f, 0.f};

  const bf16_t* Abase = A + (size_t)(bm * 128) * K;
  const bf16_t* Bbase = Bm + (size_t)(bn * 128) * K;
  const int srow = t >> 2;
  const int scol = (t & 3) * 8;

  for (int kk = 0; kk < K; kk += 32) {
    gload_lds16(Abase + (size_t)srow * K + kk + scol,        As + t * 8);
    gload_lds16(Abase + (size_t)(srow + 64) * K + kk + scol, As + 2048 + t * 8);
    gload_lds16(Bbase + (size_t)srow * K + kk + scol,        Bs + t * 8);
    gload_lds16(Bbase + (size_t)(srow + 64) * K + kk + scol, Bs + 2048 + t * 8);
    __syncthreads();
    bf16x8 a[4], b[4];
#pragma unroll
    for (int m = 0; m < 4; m++)
      a[m] = *(const bf16x8*)(As + (wr * 64 + m * 16 + qr) * 32 + g * 8);
#pragma unroll
    for (int n = 0; n < 4; n++)
      b[n] = *(const bf16x8*)(Bs + (wc * 64 + n * 16 + qr) * 32 + g * 8);
#pragma unroll
    for (int m = 0; m < 4; m++)
#pragma unroll
      for (int n = 0; n < 4; n++)
        acc[m][n] = __builtin_amdgcn_mfma_f32_16x16x32_bf16(a[m], b[n], acc[m][n], 0, 0, 0);
    __syncthreads();
  }

#pragma unroll
  for (int m = 0; m < 4; m++) {
    int row0 = bm * 128 + wr * 64 + m * 16 + g * 4;
#pragma unroll
    for (int n = 0; n < 4; n++) {
      int col = bn * 128 + wc * 64 + n * 16 + qr;
#pragma unroll
      for (int r = 0; r < 4; r++)
        C[(size_t)(row0 + r) * N + col] = (OutT)acc[m][n][r];
    }
  }
}

// ---- fused QKV GEMM + RoPE + q-scale + V-transpose: 256^2 tile, BK=64, 8-wave 8-phase ----
// Core loop identical to R10/R11's race-proven gemm256. launch_bounds (512,1): acc needs 128
// VGPR alone; the old (512,2) cap of 128 forced scratch spills.
// Epilogue: each 64-col window w = bn*4+wn of qkv [4096 x 3072] is exactly one of q/k/v of
// head w/3 (type w%3; N = 48 windows = 16 heads x 3 x 64). Thread holds cols qr+16n, so rope
// pairs (d, d+32) = (acc[m][n], acc[m][n+2]) are in-register. Writes Q/K (roped, q scaled
// 1/8) as [bh][s][64] and V transposed as [bh][d][S] directly; qkv never materialized.
__global__ __launch_bounds__(512, 1) void gemm_qkv_rope(const bf16_t* __restrict__ A,
                                                        const bf16_t* __restrict__ Bm,
                                                        const int* __restrict__ pos,
                                                        bf16_t* __restrict__ Qd,
                                                        bf16_t* __restrict__ Kd,
                                                        bf16_t* __restrict__ Vtd) {
  const int K = D_;                 // 1024
  const int NT = K >> 6;
  __shared__ bf16_t As[2][256 * 64];
  __shared__ bf16_t Bs[2][256 * 64];
  const int t = threadIdx.x;
  const int lane = t & 63, wid = t >> 6;
  const int qr = lane & 15, g = lane >> 4;
  const int wm = wid >> 2, wn = wid & 3;
  const int bm = blockIdx.x, bn = blockIdx.y;

  const bf16_t* Ab = A + (size_t)(bm * 256) * K;
  const bf16_t* Bb = Bm + (size_t)(bn * 256) * K;

  const bf16_t* srcA[4];
  const bf16_t* srcB[4];
  int ldsOff[4];
#pragma unroll
  for (int i = 0; i < 4; i++) {
    int e = t + 512 * i;
    int row = e >> 3, cs = e & 7;
    int gcol = (cs ^ (row & 7)) * 8;
    srcA[i] = Ab + (size_t)row * K + gcol;
    srcB[i] = Bb + (size_t)row * K + gcol;
    ldsOff[i] = e * 8;
  }

  f32x4 acc[8][4];
#pragma unroll
  for (int m = 0; m < 8; m++)
#pragma unroll
    for (int n = 0; n < 4; n++) acc[m][n] = (f32x4){0.f, 0.f, 0.f, 0.f};

#define RD(buf_, r_, k_) (*(const bf16x8*)((buf_) + (r_) * 64 + ((((k_) * 4 + g) ^ ((r_) & 7)) * 8)))

#pragma unroll
  for (int i = 0; i < 4; i++) gload_lds16(srcA[i], As[0] + ldsOff[i]);
#pragma unroll
  for (int i = 0; i < 4; i++) gload_lds16(srcB[i], Bs[0] + ldsOff[i]);
#pragma unroll
  for (int i = 0; i < 4; i++) gload_lds16(srcA[i] + 64, As[1] + ldsOff[i]);
#pragma unroll
  for (int i = 0; i < 4; i++) gload_lds16(srcB[i] + 64, Bs[1] + ldsOff[i]);

  for (int T = 0; T < NT; ++T) {
    bf16_t* A_c = As[T & 1];
    bf16_t* B_c = Bs[T & 1];
    if (T + 1 < NT) asm volatile("s_waitcnt vmcnt(8)" ::: "memory");
    else            asm volatile("s_waitcnt vmcnt(0)" ::: "memory");
    __builtin_amdgcn_sched_barrier(0);
    __builtin_amdgcn_s_barrier();

    const bool st = (T + 2 < NT);
    const int kt2 = (T + 2) * 64;

    bf16x8 alo[4][2], ahi[4][2], bfr[4][2];

    // ---- ph0: read a_lo (regions 0,2) + b01; MFMA m0-3 x n0-1 ----
#pragma unroll
    for (int m = 0; m < 4; m++) {
      int r = wm * 128 + m * 16 + qr;
      alo[m][0] = RD(A_c, r, 0); alo[m][1] = RD(A_c, r, 1);
    }
#pragma unroll
    for (int n = 0; n < 2; n++) {
      int r = wn * 64 + n * 16 + qr;
      bfr[n][0] = RD(B_c, r, 0); bfr[n][1] = RD(B_c, r, 1);
    }
    __builtin_amdgcn_s_barrier();
    __builtin_amdgcn_s_setprio(1);
#pragma unroll
    for (int m = 0; m < 4; m++)
#pragma unroll
      for (int n = 0; n < 2; n++)
#pragma unroll
        for (int k = 0; k < 2; k++)
          acc[m][n] = __builtin_amdgcn_mfma_f32_16x16x32_bf16(alo[m][k], bfr[n][k], acc[m][n], 0, 0, 0);
    __builtin_amdgcn_s_setprio(0);
    __builtin_amdgcn_s_barrier();

    // ---- ph1: read b23; stage T+2 A regions {0,2}; MFMA m0-3 x n2-3 ----
#pragma unroll
    for (int n = 2; n < 4; n++) {
      int r = wn * 64 + n * 16 + qr;
      bfr[n][0] = RD(B_c, r, 0); bfr[n][1] = RD(B_c, r, 1);
    }
    if (st) {
      gload_lds16(srcA[0] + kt2, A_c + ldsOff[0]);
      gload_lds16(srcA[2] + kt2, A_c + ldsOff[2]);
    }
    __builtin_amdgcn_s_barrier();
    __builtin_amdgcn_s_setprio(1);
#pragma unroll
    for (int m = 0; m < 4; m++)
#pragma unroll
      for (int n = 2; n < 4; n++)
#pragma unroll
        for (int k = 0; k < 2; k++)
          acc[m][n] = __builtin_amdgcn_mfma_f32_16x16x32_bf16(alo[m][k], bfr[n][k], acc[m][n], 0, 0, 0);
    __builtin_amdgcn_s_setprio(0);
    __builtin_amdgcn_s_barrier();

    // ---- ph2: read a_hi (regions 1,3); stage T+2 B; MFMA m4-7 x n0-1 ----
#pragma unroll
    for (int m = 0; m < 4; m++) {
      int r = wm * 128 + (m + 4) * 16 + qr;
      ahi[m][0] = RD(A_c, r, 0); ahi[m][1] = RD(A_c, r, 1);
    }
    if (st) {
      gload_lds16(srcB[0] + kt2, B_c + ldsOff[0]);
      gload_lds16(srcB[1] + kt2, B_c + ldsOff[1]);
      gload_lds16(srcB[2] + kt2, B_c + ldsOff[2]);
      gload_lds16(srcB[3] + kt2, B_c + ldsOff[3]);
    }
    __builtin_amdgcn_s_barrier();
    __builtin_amdgcn_s_setprio(1);
#pragma unroll
    for (int m = 0; m < 4; m++)
#pragma unroll
      for (int n = 0; n < 2; n++)
#pragma unroll
        for (int k = 0; k < 2; k++)
          acc[m + 4][n] = __builtin_amdgcn_mfma_f32_16x16x32_bf16(ahi[m][k], bfr[n][k], acc[m + 4][n], 0, 0, 0);
    __builtin_amdgcn_s_setprio(0);
    __builtin_amdgcn_s_barrier();

    // ---- ph3: stage T+2 A regions {1,3}; MFMA m4-7 x n2-3 ----
    if (st) {
      gload_lds16(srcA[1] + kt2, A_c + ldsOff[1]);
      gload_lds16(srcA[3] + kt2, A_c + ldsOff[3]);
    }
    __builtin_amdgcn_s_barrier();
    __builtin_amdgcn_s_setprio(1);
#pragma unroll
    for (int m = 0; m < 4; m++)
#pragma unroll
      for (int n = 2; n < 4; n++)
#pragma unroll
        for (int k = 0; k < 2; k++)
          acc[m + 4][n] = __builtin_amdgcn_mfma_f32_16x16x32_bf16(ahi[m][k], bfr[n][k], acc[m + 4][n], 0, 0, 0);
    __builtin_amdgcn_s_setprio(0);
    __builtin_amdgcn_s_barrier();
  }
#undef RD

  // ---- fused epilogue ----
  const int w = bn * 4 + wn;        // window 0..47
  const int typ = w % 3;            // 0=q, 1=k, 2=v
  const int head = w / 3;

  if (typ == 2) {
    // V window: col-in-window = 16n+qr = d; write Vt[bh][d][s], 4 consecutive s per acc.
#pragma unroll
    for (int m = 0; m < 8; m++) {
      int row0 = bm * 256 + wm * 128 + m * 16 + g * 4;
      int b = row0 >> 11, s = row0 & (S_ - 1);
#pragma unroll
      for (int n = 0; n < 4; n++) {
        int d = n * 16 + qr;
        bf16x4 o;
        o[0] = (__bf16)acc[m][n][0]; o[1] = (__bf16)acc[m][n][1];
        o[2] = (__bf16)acc[m][n][2]; o[3] = (__bf16)acc[m][n][3];
        *(bf16x4*)(Vtd + ((size_t)((b * H_ + head) * HD_ + d)) * S_ + s) = o;
      }
    }
  } else {
    // q/k window: rope pairs (d=16n+qr, d+32) = (acc[m][n], acc[m][n+2]), n in {0,1}.
    bf16_t* dstb = (typ == 0) ? Qd : Kd;
    const float qs = (typ == 0) ? 0.125f : 1.0f;
    const float l2r = 13.287712379549449f / 32.0f;
    float inv[2];
    inv[0] = exp2f(-(float)qr * l2r);
    inv[1] = exp2f(-(float)(qr + 16) * l2r);
#pragma unroll
    for (int m = 0; m < 8; m++) {
      int row0 = bm * 256 + wm * 128 + m * 16 + g * 4;
      int b = row0 >> 11;
      bf16_t* base = dstb + (size_t)(b * H_ + head) * S_ * HD_;
#pragma unroll
      for (int rr = 0; rr < 4; rr++) {
        int row = row0 + rr;
        int s = row & (S_ - 1);
        float p = (float)pos[row];
#pragma unroll
        for (int n = 0; n < 2; n++) {
          float ang = p * inv[n];
          float sn, cs;
          sincosf(ang, &sn, &cs);
          float x1 = acc[m][n][rr], x2 = acc[m][n + 2][rr];
          float o1 = (x1 * cs - x2 * sn) * qs;
          float o2 = (x2 * cs + x1 * sn) * qs;
          int d = n * 16 + qr;
          base[(size_t)s * HD_ + d] = (__bf16)o1;
          base[(size_t)s * HD_ + d + 32] = (__bf16)o2;
        }
      }
    }
  }
}

// ---------------- flash attention: split-KV (2 halves) + XCD-resident KV mapping ----------------
__global__ __launch_bounds__(256) void attn_kernel(const bf16_t* __restrict__ Q,
                                                   const bf16_t* __restrict__ K,
                                                   const bf16_t* __restrict__ Vt,
                                                   const int* __restrict__ pos,
                                                   bf16_t* __restrict__ O,
                                                   bf16_t* __restrict__ Opart,
                                                   float* __restrict__ Mst,
                                                   float* __restrict__ Lst) {
  __shared__ bf16_t Ks[2][64 * 64];
  __shared__ bf16_t Vs[2][64 * 64];

  const int t = threadIdx.x;
  const int lane = t & 63, wv = t >> 6;
  const int l31 = lane & 31, hi = lane >> 5;

  const int bid = blockIdx.x;
  const int bh = (bid & 7) * 4 + ((bid >> 3) & 3);
  const int v5 = bid >> 5;
  const int qblk = 15 - (v5 >> 1);
  const int half = v5 & 1;
  const int b = bh >> 4, h = bh & 15;
  const int q0 = qblk * 128;

  const bf16_t* Qb = Q + (size_t)bh * (S_ * HD_);
  const bf16_t* Kb = K + (size_t)bh * (S_ * HD_);
  const bf16_t* Vb = Vt + (size_t)bh * (HD_ * S_);

  const int qrow = q0 + wv * 32 + l31;

  const int prow = pos[b * S_ + qrow];
  int wmin = prow;
#pragma unroll
  for (int off = 1; off < 32; off <<= 1) wmin = min(wmin, __shfl_xor(wmin, off));

  int mp = max(pos[b * S_ + q0 + lane], pos[b * S_ + q0 + 64 + lane]);
#pragma unroll
  for (int off = 1; off < 64; off <<= 1) mp = max(mp, __shfl_xor(mp, off));
  const int nt = min(S_ / KVBLK, (mp >> 6) + 1);

  const int t0 = half * 16;
  const int t1 = min(nt, t0 + 16);
  if (t0 >= t1) return;
  const bool needs_merge = (nt > 16);

  bf16x8 qf[4];
#pragma unroll
  for (int c = 0; c < 4; c++)
    qf[c] = *(const bf16x8*)(Qb + (size_t)qrow * HD_ + c * 16 + hi * 8);

  const int r0 = t >> 3, c0 = t & 7;
  const int r1 = (t + 256) >> 3, c1 = t & 7;
  const bf16_t* KgA = Kb + (size_t)r0 * HD_ + ((c0 ^ (r0 & 7)) * 8);
  const bf16_t* KgB = Kb + (size_t)r1 * HD_ + ((c1 ^ (r1 & 7)) * 8);
  const bf16_t* VgA = Vb + (size_t)r0 * S_ + ((c0 ^ (r0 & 7)) * 8);
  const bf16_t* VgB = Vb + (size_t)r1 * S_ + ((c1 ^ (r1 & 7)) * 8);
  const int ldsA = t * 8, ldsB = (t + 256) * 8;

  f32x16 oT[2];
#pragma unroll
  for (int dt = 0; dt < 2; dt++)
#pragma unroll
    for (int r = 0; r < 16; r++) oT[dt][r] = 0.f;
  float m_run = NINF, l_run = 0.f;

  {
    const int kn = t0 * KVBLK;
    gload_lds16(KgA + (size_t)kn * HD_, Ks[0] + ldsA);
    gload_lds16(KgB + (size_t)kn * HD_, Ks[0] + ldsB);
    gload_lds16(VgA + kn, Vs[0] + ldsA);
    gload_lds16(VgB + kn, Vs[0] + ldsB);
  }
  __syncthreads();

  for (int kt = t0; kt < t1; ++kt) {
    const int k0 = kt * KVBLK;
    const int cur = kt & 1;
    if (kt + 1 < t1) {
      const int kn = (kt + 1) * KVBLK;
      gload_lds16(KgA + (size_t)kn * HD_, Ks[cur ^ 1] + ldsA);
      gload_lds16(KgB + (size_t)kn * HD_, Ks[cur ^ 1] + ldsB);
      gload_lds16(VgA + kn, Vs[cur ^ 1] + ldsA);
      gload_lds16(VgB + kn, Vs[cur ^ 1] + ldsB);
    }
    const bf16_t* Kc = Ks[cur];
    const bf16_t* Vc = Vs[cur];

    f32x16 s0, s1;
#pragma unroll
    for (int r = 0; r < 16; r++) { s0[r] = 0.f; s1[r] = 0.f; }
    __builtin_amdgcn_s_setprio(1);
#pragma unroll
    for (int c = 0; c < 4; c++) {
      const int c2 = c * 2 + hi;
      const int kr0 = l31;
      const int kr1 = 32 + l31;
      bf16x8 kf0 = *(const bf16x8*)(Kc + kr0 * 64 + ((c2 ^ (kr0 & 7)) * 8));
      bf16x8 kf1 = *(const bf16x8*)(Kc + kr1 * 64 + ((c2 ^ (kr1 & 7)) * 8));
      s0 = __builtin_amdgcn_mfma_f32_32x32x16_bf16(kf0, qf[c], s0, 0, 0, 0);
      s1 = __builtin_amdgcn_mfma_f32_32x32x16_bf16(kf1, qf[c], s1, 0, 0, 0);
    }
    __builtin_amdgcn_s_setprio(0);

    float p0[16], p1[16];
    if (k0 + 63 > wmin) {
#pragma unroll
      for (int r = 0; r < 16; r++) {
        int koff = (r & 3) + 8 * (r >> 2) + 4 * hi;
        p0[r] = (k0 + koff <= prow) ? s0[r] : NINF;
        p1[r] = (k0 + 32 + koff <= prow) ? s1[r] : NINF;
      }
    } else {
#pragma unroll
      for (int r = 0; r < 16; r++) { p0[r] = s0[r]; p1[r] = s1[r]; }
    }

    float tm = NINF;
#pragma unroll
    for (int r = 0; r < 16; r++) tm = fmaxf(tm, fmaxf(p0[r], p1[r]));
    tm = fmaxf(tm, __shfl_xor(tm, 32));
    if (__any(tm > m_run + 8.0f)) {
      float mn = fmaxf(fmaxf(m_run, tm), -1e30f);
      float scale = exp2f((m_run - mn) * L2E);
      l_run *= scale;
#pragma unroll
      for (int dt = 0; dt < 2; dt++)
#pragma unroll
        for (int r = 0; r < 16; r++) oT[dt][r] *= scale;
      m_run = mn;
    }
    const float mnl = (m_run == NINF) ? 3.0e38f : m_run * L2E;
    float rs = 0.f;
#pragma unroll
    for (int r = 0; r < 16; r++) {
      p0[r] = exp2f(p0[r] * L2E - mnl);
      p1[r] = exp2f(p1[r] * L2E - mnl);
      rs += p0[r] + p1[r];
    }
    rs += __shfl_xor(rs, 32);
    l_run += rs;

#pragma unroll
    for (int kc = 0; kc < 4; kc++) {
      const float* P = (kc < 2) ? p0 : p1;
      const int rb = (kc & 1) * 8;
      uint32_t xa0 = packbf(P[rb + 0], P[rb + 1]);
      uint32_t xa1 = packbf(P[rb + 2], P[rb + 3]);
      uint32_t xb0 = packbf(P[rb + 4], P[rb + 5]);
      uint32_t xb1 = packbf(P[rb + 6], P[rb + 7]);
      uint32_t sa0 = (uint32_t)__shfl_xor((int)xa0, 32);
      uint32_t sa1 = (uint32_t)__shfl_xor((int)xa1, 32);
      uint32_t sb0 = (uint32_t)__shfl_xor((int)xb0, 32);
      uint32_t sb1 = (uint32_t)__shfl_xor((int)xb1, 32);
      union { uint32_t u[4]; bf16x8 v; } pf;
      pf.u[0] = hi ? sb0 : xa0;
      pf.u[1] = hi ? sb1 : xa1;
      pf.u[2] = hi ? xb0 : sa0;
      pf.u[3] = hi ? xb1 : sa1;
      __builtin_amdgcn_s_setprio(1);
#pragma unroll
      for (int dt = 0; dt < 2; dt++) {
        const int vr = dt * 32 + l31;
        const int c2 = kc * 2 + hi;
        bf16x8 vf = *(const bf16x8*)(Vc + vr * 64 + ((c2 ^ (vr & 7)) * 8));
        oT[dt] = __builtin_amdgcn_mfma_f32_32x32x16_bf16(vf, pf.v, oT[dt], 0, 0, 0);
      }
      __builtin_amdgcn_s_setprio(0);
    }

    __syncthreads();
  }

  const float rl = needs_merge ? 1.0f : ((l_run > 0.f) ? 1.0f / l_run : 0.f);
  bf16_t* Ot = (bf16_t*)Ks + wv * 2048;
#pragma unroll
  for (int dt = 0; dt < 2; dt++)
#pragma unroll
    for (int r = 0; r < 16; r++) {
      int chunk = dt * 4 + (r >> 2);
      int el = (r & 3) + 4 * hi;
      Ot[l31 * 64 + ((chunk ^ (l31 & 7)) * 8) + el] = (__bf16)(oT[dt][r] * rl);
    }
  __syncthreads();
  if (needs_merge) {
    bf16_t* dst = Opart + (((size_t)(half * 32 + bh) * 16 + qblk) * 128) * 64;
#pragma unroll
    for (int it = 0; it < 4; it++) {
      int qr2 = (lane >> 3) + it * 8;
      int cc = lane & 7;
      bf16x8 vv = *(const bf16x8*)(Ot + qr2 * 64 + ((cc ^ (qr2 & 7)) * 8));
      *(bf16x8*)(&dst[(size_t)(wv * 32 + qr2) * 64 + cc * 8]) = vv;
    }
    if (hi == 0) {
      size_t sidx = ((size_t)(half * 32 + bh) * 16 + qblk) * 128 + wv * 32 + l31;
      Mst[sidx] = m_run;
      Lst[sidx] = l_run;
    }
  } else {
#pragma unroll
    for (int it = 0; it < 4; it++) {
      int qr2 = (lane >> 3) + it * 8;
      int cc = lane & 7;
      bf16x8 vv = *(const bf16x8*)(Ot + qr2 * 64 + ((cc ^ (qr2 & 7)) * 8));
      *(bf16x8*)(&O[(size_t)(b * S_ + q0 + wv * 32 + qr2) * D_ + h * 64 + cc * 8]) = vv;
    }
  }
}

// ---------------- split-KV merge ----------------
__global__ __launch_bounds__(256) void attn_merge_kernel(const bf16_t* __restrict__ Opart,
                                                         const float* __restrict__ Mst,
                                                         const float* __restrict__ Lst,
                                                         const int* __restrict__ pos,
                                                         bf16_t* __restrict__ O) {
  __shared__ int wmax_s[4];
  const int t = threadIdx.x;
  const int bid = blockIdx.x;
  const int bh = (bid & 7) * 4 + ((bid >> 3) & 3);
  const int qblk = 15 - (bid >> 5);
  const int b = bh >> 4, h = bh & 15;
  const int q0 = qblk * 128;

  int p = pos[b * S_ + q0 + (t & 127)];
#pragma unroll
  for (int off = 1; off < 64; off <<= 1) p = max(p, __shfl_xor(p, off));
  if ((t & 63) == 0) wmax_s[t >> 6] = p;
  __syncthreads();
  int mp = max(max(wmax_s[0], wmax_s[1]), max(wmax_s[2], wmax_s[3]));
  if ((mp >> 6) + 1 <= 16) return;

  const int r = t >> 1, dh = (t & 1) * 32;
  const size_t s0i = ((size_t)(0 * 32 + bh) * 16 + qblk) * 128 + r;
  const size_t s1i = ((size_t)(1 * 32 + bh) * 16 + qblk) * 128 + r;
  float m0 = Mst[s0i], l0 = Lst[s0i];
  float m1 = Mst[s1i], l1 = Lst[s1i];
  float m = fmaxf(fmaxf(m0, m1), -1e30f);
  float w0 = exp2f((m0 - m) * L2E);
  float w1 = exp2f((m1 - m) * L2E);
  float lt = l0 * w0 + l1 * w1;
  float rl = (lt > 0.f) ? 1.0f / lt : 0.f;
  w0 *= rl; w1 *= rl;
  const bf16_t* pa = Opart + s0i * 64 + dh;
  const bf16_t* pb = Opart + s1i * 64 + dh;
  bf16_t* dst = O + (size_t)(b * S_ + q0 + r) * D_ + h * 64 + dh;
#pragma unroll
  for (int c = 0; c < 4; c++) {
    bf16x8 a = *(const bf16x8*)(pa + c * 8);
    bf16x8 bb = *(const bf16x8*)(pb + c * 8);
    bf16x8 o;
#pragma unroll
    for (int j = 0; j < 8; j++)
      o[j] = (__bf16)((float)a[j] * w0 + (float)bb[j] * w1);
    *(bf16x8*)(dst + c * 8) = o;
  }
}

extern "C" void kernel_launch(void* const* d_in, const int* in_sizes, int n_in,
                              void* d_out, int out_size, void* d_ws, size_t ws_size,
                              hipStream_t stream) {
  const float* inputs = (const float*)d_in[0];
  const int* positions = (const int*)d_in[1];
  const float* W_in = (const float*)d_in[2];
  const float* W_out = (const float*)d_in[3];
  float* out = (float*)d_out;

  bf16_t* X_bf = (bf16_t*)d_ws;
  bf16_t* Win_bf = X_bf + (size_t)4096 * 1024;
  bf16_t* Wout_bf = Win_bf + (size_t)3072 * 1024;
  bf16_t* scratch = Wout_bf + (size_t)1024 * 1024;   // 25.2MB region (ex-qkv)
  bf16_t* Qb = scratch + (size_t)4096 * 3072;
  bf16_t* Kb = Qb + (size_t)B_ * H_ * S_ * HD_;
  bf16_t* Vtb = Kb + (size_t)B_ * H_ * S_ * HD_;
  bf16_t* Ob = Vtb + (size_t)B_ * H_ * S_ * HD_;

  // split-KV partials live in the scratch region; every index the merge kernel
  // reads (nt>16 paths) is fully rewritten by attn_kernel each launch.
  bf16_t* Opart = scratch;
  float* Mst = (float*)(scratch + (size_t)2 * 32 * 16 * 128 * 64);
  float* Lst = Mst + (size_t)2 * 32 * 16 * 128;

  cast3_bf16_kernel<<<dim3(2048), dim3(256), 0, stream>>>(
      inputs, X_bf, (4096 * 1024) / 4,
      W_in, Win_bf, (3072 * 1024) / 4,
      W_out, Wout_bf, (1024 * 1024) / 4);

  gemm_qkv_rope<<<dim3(16, 12), dim3(512), 0, stream>>>(X_bf, Win_bf, positions, Qb, Kb, Vtb);

  attn_kernel<<<dim3(1024), dim3(256), 0, stream>>>(Qb, Kb, Vtb, positions, Ob, Opart, Mst, Lst);
  attn_merge_kernel<<<dim3(512), dim3(256), 0, stream>>>(Opart, Mst, Lst, positions, Ob);

  gemm_bt<float><<<dim3(32, 8), dim3(256), 0, stream>>>(Ob, Wout_bf, out, 4096, 1024, 1024);
}